// Round 14
// baseline (216.919 us; speedup 1.0000x reference)
//
#include <hip/hip_runtime.h>
#include <hip/hip_bf16.h>
#include <hip/hip_fp16.h>
#include <stdint.h>

typedef _Float16 half_t;
typedef _Float16 half8 __attribute__((ext_vector_type(8)));
typedef float f32x4 __attribute__((ext_vector_type(4)));

#define NN 4096
// ws layout (bytes). S1: fp16 hi/lo [64][512][64] hybrid; x1: SINGLE fp16 in
// s1hi's region (s1 dead after layer-1 gemm); y aliases xp (dead after k2e).
#define OFF_W1THI  0u
#define OFF_W1TLO  16384u
#define OFF_S1HI   32768u
#define OFF_S1LO   (32768u + 4194304u)
#define OFF_XP0    (32768u + 2u*4194304u)
#define OFF_XP1    (OFF_XP0 + 8388608u)
// total 25,198,592 bytes (proven footprint)

__device__ __forceinline__ float sigmoidf_(float x) { return 1.f / (1.f + __expf(-x)); }
__device__ __forceinline__ float tanhf_(float x)    { return 1.f - 2.f / (__expf(2.f * x) + 1.f); }

// ---- K0: transpose + hi/lo split W1 [96][64] -> W1t [64][96] fp16 pairs
__global__ void prep_w1t(const float* __restrict__ w1,
                         half_t* __restrict__ whi, half_t* __restrict__ wlo) {
    int i = blockIdx.x * 256 + threadIdx.x;
    if (i >= 96 * 64) return;
    int c = i >> 6, d = i & 63;
    float v = w1[i];
    half_t h = (half_t)v;
    whi[d * 96 + c] = h;
    wlo[d * 96 + c] = (half_t)(v - (float)h);
}

// ---- K1: S1[kb][j][kc] (j=b*64+d) = sum_c combined[b][n][c]*W1[c][d], 3-pass fp16
__global__ __launch_bounds__(256) void k1_gemm(
    const float* __restrict__ inp, const float* __restrict__ hcur,
    const half_t* __restrict__ wthi, const half_t* __restrict__ wtlo,
    half_t* __restrict__ s1hi, half_t* __restrict__ s1lo)
{
    __shared__ half_t Ch[64 * 96], Cl[64 * 96], Wh[64 * 96], Wl[64 * 96];
    const int t = threadIdx.x;
    const int l = t & 63, w = t >> 6, lr = l & 15, lg = l >> 4;
    const int b = blockIdx.x >> 6;
    const int kb = blockIdx.x & 63;
    const int nBase = kb * 64;

    {
        const uint32_t* sh = (const uint32_t*)wthi;
        const uint32_t* sl = (const uint32_t*)wtlo;
        uint32_t* dh = (uint32_t*)Wh;
        uint32_t* dl = (uint32_t*)Wl;
        for (int i = t; i < 3072; i += 256) { dh[i] = sh[i]; dl[i] = sl[i]; }
    }
#pragma unroll
    for (int i = 0; i < 6; ++i) {
        int f4 = t + i * 256;
        int row = f4 / 24, slot = f4 % 24;
        int n = nBase + row;
        f32x4 v; int c0;
        if (slot < 8) { c0 = slot * 4; v = *(const f32x4*)(inp + ((size_t)b * NN + n) * 32 + c0); }
        else { c0 = 32 + (slot - 8) * 4; v = *(const f32x4*)(hcur + ((size_t)b * NN + n) * 64 + (c0 - 32)); }
#pragma unroll
        for (int jj = 0; jj < 4; ++jj) {
            float x = v[jj];
            half_t hh = (half_t)x;
            Ch[row * 96 + c0 + jj] = hh;
            Cl[row * 96 + c0 + jj] = (half_t)(x - (float)hh);
        }
    }
    __syncthreads();

    const f32x4 z = {0.f, 0.f, 0.f, 0.f};
    f32x4 acc[4] = {z, z, z, z};
#pragma unroll
    for (int kk = 0; kk < 3; ++kk) {
        const int qo = (w * 16 + lr) * 96 + kk * 32 + lg * 8;
        half8 cf_h = *(const half8*)(Ch + qo);
        half8 cf_l = *(const half8*)(Cl + qo);
#pragma unroll
        for (int dt = 0; dt < 4; ++dt) {
            const int po = (dt * 16 + lr) * 96 + kk * 32 + lg * 8;
            half8 wf_h = *(const half8*)(Wh + po);
            half8 wf_l = *(const half8*)(Wl + po);
            acc[dt] = __builtin_amdgcn_mfma_f32_16x16x32_f16(wf_h, cf_h, acc[dt], 0, 0, 0);
            acc[dt] = __builtin_amdgcn_mfma_f32_16x16x32_f16(wf_h, cf_l, acc[dt], 0, 0, 0);
            acc[dt] = __builtin_amdgcn_mfma_f32_16x16x32_f16(wf_l, cf_h, acc[dt], 0, 0, 0);
        }
    }
    const int kc = w * 16 + lr;
#pragma unroll
    for (int dt = 0; dt < 4; ++dt)
#pragma unroll
        for (int j4 = 0; j4 < 4; ++j4) {
            int d = dt * 16 + lg * 4 + j4;
            float v = acc[dt][j4];
            half_t hh = (half_t)v;
            size_t o = ((size_t)kb * 512 + b * 64 + d) * 64 + kc;
            s1hi[o] = hh;
            s1lo[o] = (half_t)(v - (float)hh);
        }
}

// ---- K2/K3 unified: C[m][j] = sum_n (adj*mask)[m,n] * X[n][j]
// M=4096, N(j)=512, K=4096; BM=128, BN=64, BK=64, ks x2 partials.
// 512 threads = 8 waves (4m x 2n), wave tile 32x32 (fragment math = r13).
// GRID 512 -> 2 resident blocks/CU (LDS 48KB/24KB, capacity 3/4): co-resident
// blocks overlap each other's barrier/staging stalls (m114 mechanism) — the
// missing ingredient in rounds 5-13 (grid 256 = exactly 1 block/CU).
// Single-buffered LDS, reg prefetch, sched_barrier fences.
// PASSES=3 (layer 1): A hi/lo + X hi/lo; PASSES=1 (layer 2): single fp16.
template<int PASSES>
__global__ __launch_bounds__(512) void gemm_bn(
    const float* __restrict__ adj, const float* __restrict__ mask,
    const half_t* __restrict__ xhi, const half_t* __restrict__ xlo,
    float* __restrict__ out0, float* __restrict__ out1)
{
    __shared__ half_t Ah[128 * 64];
    __shared__ half_t Al[PASSES == 3 ? 128 * 64 : 4];
    __shared__ half_t Xh[64 * 64];
    __shared__ half_t Xl[PASSES == 3 ? 64 * 64 : 4];
    const int t = threadIdx.x;
    const int l = t & 63, w = t >> 6, lr = l & 15, lg = l >> 4;
    const int wm = w >> 1, wn = w & 1;            // 4 m-tiles x 2 n-tiles
    const int bx = blockIdx.x;
    const int mt_ = bx & 31, ks = (bx >> 5) & 1, nb = bx >> 6;   // nb 0..7
    const int mBase = mt_ * 128, jBase = nb * 64;
    float* __restrict__ outp = ks ? out1 : out0;

    const f32x4 z = {0.f, 0.f, 0.f, 0.f};
    f32x4 acc[2][2] = {{z, z}, {z, z}};

    // staging slots: A = 128 rows x 8 chunks, 2 chunks/thread (contig 64B);
    //                X = 64 rows x 8 chunks, 1 chunk/thread.
    const int arow = t >> 2, akc = (t & 3) * 2;
    const int ab0 = (arow * 128 + akc * 16) ^ ((arow & 7) << 4);
    const int ab1 = (arow * 128 + (akc + 1) * 16) ^ ((arow & 7) << 4);
    const int xrow = t >> 3, xkc = t & 7;
    const int xb = (xrow * 128 + xkc * 16) ^ ((xrow & 7) << 4);

    // prefetch registers (tile it+1)
    f32x4 pa0, pa1, pa2, pa3, pm0, pm1, pm2, pm3;
    half8 pxh, pxl;

#define ISSUE_LOADS(IT)                                                          \
    {                                                                            \
        const int kb = ks * 32 + (IT);                                           \
        size_t ga = (size_t)(mBase + arow) * NN + kb * 64 + akc * 8;             \
        pa0 = *(const f32x4*)(adj + ga);                                         \
        pa1 = *(const f32x4*)(adj + ga + 4);                                     \
        pa2 = *(const f32x4*)(adj + ga + 8);                                     \
        pa3 = *(const f32x4*)(adj + ga + 12);                                    \
        pm0 = *(const f32x4*)(mask + ga);                                        \
        pm1 = *(const f32x4*)(mask + ga + 4);                                    \
        pm2 = *(const f32x4*)(mask + ga + 8);                                    \
        pm3 = *(const f32x4*)(mask + ga + 12);                                   \
        size_t gx = ((size_t)kb * 512 + jBase + xrow) * 64 + xkc * 8;            \
        pxh = *(const half8*)(xhi + gx);                                         \
        if constexpr (PASSES == 3) pxl = *(const half8*)(xlo + gx);              \
    }

#define CONVERT_WRITE()                                                          \
    {                                                                            \
        half8 hv0, lv0, hv1, lv1;                                                \
        _Pragma("unroll")                                                        \
        for (int jj = 0; jj < 4; ++jj) {                                         \
            float q0 = pa0[jj] * pm0[jj];                                        \
            float q1 = pa1[jj] * pm1[jj];                                        \
            float q2 = pa2[jj] * pm2[jj];                                        \
            float q3 = pa3[jj] * pm3[jj];                                        \
            half_t h0 = (half_t)q0, h1 = (half_t)q1;                             \
            half_t h2 = (half_t)q2, h3 = (half_t)q3;                             \
            hv0[jj] = h0; hv0[jj + 4] = h1;                                      \
            hv1[jj] = h2; hv1[jj + 4] = h3;                                      \
            if constexpr (PASSES == 3) {                                         \
                lv0[jj] = (half_t)(q0 - (float)h0);                              \
                lv0[jj + 4] = (half_t)(q1 - (float)h1);                          \
                lv1[jj] = (half_t)(q2 - (float)h2);                              \
                lv1[jj + 4] = (half_t)(q3 - (float)h3);                          \
            }                                                                    \
        }                                                                        \
        *(half8*)((char*)Ah + ab0) = hv0;                                        \
        *(half8*)((char*)Ah + ab1) = hv1;                                        \
        *(half8*)((char*)Xh + xb) = pxh;                                         \
        if constexpr (PASSES == 3) {                                             \
            *(half8*)((char*)Al + ab0) = lv0;                                    \
            *(half8*)((char*)Al + ab1) = lv1;                                    \
            *(half8*)((char*)Xl + xb) = pxl;                                     \
        }                                                                        \
    }

    ISSUE_LOADS(0);

    for (int it = 0; it < 32; ++it) {
        CONVERT_WRITE();                           // LDS <- regs (tile it)
        __syncthreads();                           // tile ready
        if (it + 1 < 32) ISSUE_LOADS(it + 1);      // next-tile loads in flight
        __builtin_amdgcn_sched_barrier(0);         // ...pinned before compute
#pragma unroll
        for (int kk = 0; kk < 2; ++kk) {
            half8 fa_h[2], fa_l[2], fx_h[2], fx_l[2];
#pragma unroll
            for (int mt = 0; mt < 2; ++mt) {
                int r = wm * 32 + mt * 16 + lr;
                int byte = (r * 128 + kk * 64 + lg * 16) ^ ((r & 7) << 4);
                fa_h[mt] = *(const half8*)((const char*)Ah + byte);
                if constexpr (PASSES == 3)
                    fa_l[mt] = *(const half8*)((const char*)Al + byte);
            }
#pragma unroll
            for (int nt = 0; nt < 2; ++nt) {
                int r = wn * 32 + nt * 16 + lr;
                int byte = (r * 128 + kk * 64 + lg * 16) ^ ((r & 7) << 4);
                fx_h[nt] = *(const half8*)((const char*)Xh + byte);
                if constexpr (PASSES == 3)
                    fx_l[nt] = *(const half8*)((const char*)Xl + byte);
            }
            __builtin_amdgcn_sched_barrier(0);      // batch reads, one drain
#pragma unroll
            for (int mt = 0; mt < 2; ++mt)
#pragma unroll
                for (int nt = 0; nt < 2; ++nt) {
                    acc[mt][nt] = __builtin_amdgcn_mfma_f32_16x16x32_f16(fa_h[mt], fx_h[nt], acc[mt][nt], 0, 0, 0);
                    if constexpr (PASSES == 3) {
                        acc[mt][nt] = __builtin_amdgcn_mfma_f32_16x16x32_f16(fa_l[mt], fx_h[nt], acc[mt][nt], 0, 0, 0);
                        acc[mt][nt] = __builtin_amdgcn_mfma_f32_16x16x32_f16(fa_h[mt], fx_l[nt], acc[mt][nt], 0, 0, 0);
                    }
                }
        }
        __syncthreads();                           // all reads done before rewrite
    }

    // C store: row m' = mBase+wm*32+mt*16+lg*4+j4, col j' = jBase+wn*32+nt*16+lr
#pragma unroll
    for (int mt = 0; mt < 2; ++mt)
#pragma unroll
        for (int nt = 0; nt < 2; ++nt) {
            int jcol = jBase + wn * 32 + nt * 16 + lr;
#pragma unroll
            for (int j4 = 0; j4 < 4; ++j4) {
                int mrow = mBase + wm * 32 + mt * 16 + lg * 4 + j4;
                outp[(size_t)mrow * 512 + jcol] = acc[mt][nt][j4];
            }
        }
#undef ISSUE_LOADS
#undef CONVERT_WRITE
}

// ---- K2e: x1[kb][j][kc] = relu(xp0+xp1+b1[j&63]) — SINGLE fp16 (one-hop error)
__global__ __launch_bounds__(256) void k2e(
    const float* __restrict__ p0, const float* __restrict__ p1,
    const float* __restrict__ b1,
    half_t* __restrict__ x1s)
{
    int base = blockIdx.x * 256 + threadIdx.x;
#pragma unroll
    for (int rpt = 0; rpt < 4; ++rpt) {
        int idx4 = base + rpt * 131072;
        int m = idx4 >> 7, jq = idx4 & 127;
        int j0 = jq * 4, d0 = j0 & 63;
        size_t e = (size_t)m * 512 + j0;
        f32x4 v = *(const f32x4*)(p0 + e);
        f32x4 u = *(const f32x4*)(p1 + e);
        f32x4 bb = *(const f32x4*)(b1 + d0);
        size_t obase = ((size_t)(m >> 6) * 512 + j0) * 64 + (m & 63);
#pragma unroll
        for (int jj = 0; jj < 4; ++jj) {
            float x = v[jj] + u[jj] + bb[jj];
            x = fmaxf(x, 0.f);
            x1s[obase + (size_t)jj * 64] = (half_t)x;
        }
    }
}

// ---- K4: cc = Y@W2 + b2 (fp32, full W2 in LDS, static acc indices) + LSTM pointwise.
__global__ __launch_bounds__(256) void k4_final(
    const float* __restrict__ y0, const float* __restrict__ y1,
    const float* __restrict__ w2, const float* __restrict__ b2,
    const float* __restrict__ ccur,
    float* __restrict__ outh, float* __restrict__ outc)
{
    __shared__ float Yt[64 * 64];
    __shared__ float W2s[64 * 256];
    const int t = threadIdx.x;
    const int cb = t & 15, rb = t >> 4;
    const int rowBase = blockIdx.x * 64;
    const int bIdx = rowBase >> 12, mBase = rowBase & 4095;

#pragma unroll
    for (int i = 0; i < 4; ++i) {
        int id4 = t + i * 256;
        int r = id4 >> 4, dc = id4 & 15;
        size_t g = (size_t)(mBase + r) * 512 + bIdx * 64 + dc * 4;
        f32x4 v = *(const f32x4*)(y0 + g);
        f32x4 u = *(const f32x4*)(y1 + g);
#pragma unroll
        for (int jj = 0; jj < 4; ++jj) Yt[(dc * 4 + jj) * 64 + r] = v[jj] + u[jj];
    }
#pragma unroll
    for (int i = 0; i < 16; ++i) {
        int id4 = t + i * 256;
        *(f32x4*)(W2s + id4 * 4) = *(const f32x4*)(w2 + id4 * 4);
    }
    __syncthreads();

    const f32x4 z = {0.f, 0.f, 0.f, 0.f};
    f32x4 accG[4][4];
#pragma unroll
    for (int g = 0; g < 4; ++g)
#pragma unroll
        for (int r8 = 0; r8 < 4; ++r8) accG[g][r8] = z;

    for (int d = 0; d < 64; ++d) {
        f32x4 y4 = *(const f32x4*)(Yt + d * 64 + rb * 4);
#pragma unroll
        for (int g = 0; g < 4; ++g) {
            f32x4 w4 = *(const f32x4*)(W2s + d * 256 + g * 64 + cb * 4);
#pragma unroll
            for (int r8 = 0; r8 < 4; ++r8) accG[g][r8] += w4 * y4[r8];
        }
    }

    float b2i[4], b2f[4], b2o[4], b2g[4];
#pragma unroll
    for (int jj = 0; jj < 4; ++jj) {
        b2i[jj] = b2[0 * 64 + cb * 4 + jj];
        b2f[jj] = b2[1 * 64 + cb * 4 + jj];
        b2o[jj] = b2[2 * 64 + cb * 4 + jj];
        b2g[jj] = b2[3 * 64 + cb * 4 + jj];
    }
#pragma unroll
    for (int r8 = 0; r8 < 4; ++r8) {
        int row = rowBase + rb * 4 + r8;
        f32x4 c4 = *(const f32x4*)(ccur + (size_t)row * 64 + cb * 4);
        f32x4 hv, cv;
#pragma unroll
        for (int jj = 0; jj < 4; ++jj) {
            float ii = sigmoidf_(accG[0][r8][jj] + b2i[jj]);
            float ff = sigmoidf_(accG[1][r8][jj] + b2f[jj]);
            float oo = sigmoidf_(accG[2][r8][jj] + b2o[jj]);
            float gg = tanhf_(accG[3][r8][jj] + b2g[jj]);
            float cn = ff * c4[jj] + ii * gg;
            float hn = oo * tanhf_(cn);
            hv[jj] = hn;
            cv[jj] = cn;
        }
        *(f32x4*)(outh + (size_t)row * 64 + cb * 4) = hv;
        *(f32x4*)(outc + (size_t)row * 64 + cb * 4) = cv;
    }
}

extern "C" void kernel_launch(void* const* d_in, const int* in_sizes, int n_in,
                              void* d_out, int out_size, void* d_ws, size_t ws_size,
                              hipStream_t stream) {
    const float* inp   = (const float*)d_in[0];
    const float* hcur  = (const float*)d_in[1];
    const float* ccur  = (const float*)d_in[2];
    const float* adj   = (const float*)d_in[3];
    const float* w1    = (const float*)d_in[4];
    const float* mask1 = (const float*)d_in[5];
    const float* b1    = (const float*)d_in[6];
    const float* w2    = (const float*)d_in[7];
    const float* mask2 = (const float*)d_in[8];
    const float* b2    = (const float*)d_in[9];

    char* ws = (char*)d_ws;
    half_t* w1thi = (half_t*)(ws + OFF_W1THI);
    half_t* w1tlo = (half_t*)(ws + OFF_W1TLO);
    half_t* s1hi  = (half_t*)(ws + OFF_S1HI);
    half_t* s1lo  = (half_t*)(ws + OFF_S1LO);
    half_t* x1s   = (half_t*)(ws + OFF_S1HI);   // alias: s1 dead after layer-1 gemm
    float*  xp0   = (float*)(ws + OFF_XP0);
    float*  xp1   = (float*)(ws + OFF_XP1);
    float*  y0    = (float*)(ws + OFF_XP0);     // alias: xp dead after k2e
    float*  y1    = (float*)(ws + OFF_XP1);

    float* hout = (float*)d_out;
    float* cout = hout + (size_t)8 * 4096 * 64;

    prep_w1t<<<24, 256, 0, stream>>>(w1, w1thi, w1tlo);
    k1_gemm<<<512, 256, 0, stream>>>(inp, hcur, w1thi, w1tlo, s1hi, s1lo);
    gemm_bn<3><<<512, 512, 0, stream>>>(adj, mask1, s1hi, s1lo, xp0, xp1);
    k2e<<<512, 256, 0, stream>>>(xp0, xp1, b1, x1s);
    gemm_bn<1><<<512, 512, 0, stream>>>(adj, mask2, x1s, x1s, y0, y1);
    k4_final<<<512, 256, 0, stream>>>(y0, y1, w2, b2, ccur, hout, cout);
}

// Round 15
// 165.171 us; speedup vs baseline: 1.3133x; 1.3133x over previous
//
#include <hip/hip_runtime.h>
#include <hip/hip_bf16.h>
#include <hip/hip_fp16.h>
#include <stdint.h>

typedef _Float16 half_t;
typedef _Float16 half8 __attribute__((ext_vector_type(8)));
typedef float f32x4 __attribute__((ext_vector_type(4)));

#define NN 4096
// ws layout (bytes). S1: fp16 hi/lo [64][512][64] hybrid; x1: SINGLE fp16 in
// s1hi's region (s1 dead after layer-1 gemm); y aliases xp (dead after k2e).
#define OFF_W1THI  0u
#define OFF_W1TLO  16384u
#define OFF_S1HI   32768u
#define OFF_S1LO   (32768u + 4194304u)
#define OFF_XP0    (32768u + 2u*4194304u)
#define OFF_XP1    (OFF_XP0 + 8388608u)
// total 25,198,592 bytes (proven footprint)

__device__ __forceinline__ float sigmoidf_(float x) { return 1.f / (1.f + __expf(-x)); }
__device__ __forceinline__ float tanhf_(float x)    { return 1.f - 2.f / (__expf(2.f * x) + 1.f); }

// ---- K0: transpose + hi/lo split W1 [96][64] -> W1t [64][96] fp16 pairs
__global__ void prep_w1t(const float* __restrict__ w1,
                         half_t* __restrict__ whi, half_t* __restrict__ wlo) {
    int i = blockIdx.x * 256 + threadIdx.x;
    if (i >= 96 * 64) return;
    int c = i >> 6, d = i & 63;
    float v = w1[i];
    half_t h = (half_t)v;
    whi[d * 96 + c] = h;
    wlo[d * 96 + c] = (half_t)(v - (float)h);
}

// ---- K1: S1[kb][j][kc] (j=b*64+d) = sum_c combined[b][n][c]*W1[c][d], 3-pass fp16
__global__ __launch_bounds__(256) void k1_gemm(
    const float* __restrict__ inp, const float* __restrict__ hcur,
    const half_t* __restrict__ wthi, const half_t* __restrict__ wtlo,
    half_t* __restrict__ s1hi, half_t* __restrict__ s1lo)
{
    __shared__ half_t Ch[64 * 96], Cl[64 * 96], Wh[64 * 96], Wl[64 * 96];
    const int t = threadIdx.x;
    const int l = t & 63, w = t >> 6, lr = l & 15, lg = l >> 4;
    const int b = blockIdx.x >> 6;
    const int kb = blockIdx.x & 63;
    const int nBase = kb * 64;

    {
        const uint32_t* sh = (const uint32_t*)wthi;
        const uint32_t* sl = (const uint32_t*)wtlo;
        uint32_t* dh = (uint32_t*)Wh;
        uint32_t* dl = (uint32_t*)Wl;
        for (int i = t; i < 3072; i += 256) { dh[i] = sh[i]; dl[i] = sl[i]; }
    }
#pragma unroll
    for (int i = 0; i < 6; ++i) {
        int f4 = t + i * 256;
        int row = f4 / 24, slot = f4 % 24;
        int n = nBase + row;
        f32x4 v; int c0;
        if (slot < 8) { c0 = slot * 4; v = *(const f32x4*)(inp + ((size_t)b * NN + n) * 32 + c0); }
        else { c0 = 32 + (slot - 8) * 4; v = *(const f32x4*)(hcur + ((size_t)b * NN + n) * 64 + (c0 - 32)); }
#pragma unroll
        for (int jj = 0; jj < 4; ++jj) {
            float x = v[jj];
            half_t hh = (half_t)x;
            Ch[row * 96 + c0 + jj] = hh;
            Cl[row * 96 + c0 + jj] = (half_t)(x - (float)hh);
        }
    }
    __syncthreads();

    const f32x4 z = {0.f, 0.f, 0.f, 0.f};
    f32x4 acc[4] = {z, z, z, z};
#pragma unroll
    for (int kk = 0; kk < 3; ++kk) {
        const int qo = (w * 16 + lr) * 96 + kk * 32 + lg * 8;
        half8 cf_h = *(const half8*)(Ch + qo);
        half8 cf_l = *(const half8*)(Cl + qo);
#pragma unroll
        for (int dt = 0; dt < 4; ++dt) {
            const int po = (dt * 16 + lr) * 96 + kk * 32 + lg * 8;
            half8 wf_h = *(const half8*)(Wh + po);
            half8 wf_l = *(const half8*)(Wl + po);
            acc[dt] = __builtin_amdgcn_mfma_f32_16x16x32_f16(wf_h, cf_h, acc[dt], 0, 0, 0);
            acc[dt] = __builtin_amdgcn_mfma_f32_16x16x32_f16(wf_h, cf_l, acc[dt], 0, 0, 0);
            acc[dt] = __builtin_amdgcn_mfma_f32_16x16x32_f16(wf_l, cf_h, acc[dt], 0, 0, 0);
        }
    }
    const int kc = w * 16 + lr;
#pragma unroll
    for (int dt = 0; dt < 4; ++dt)
#pragma unroll
        for (int j4 = 0; j4 < 4; ++j4) {
            int d = dt * 16 + lg * 4 + j4;
            float v = acc[dt][j4];
            half_t hh = (half_t)v;
            size_t o = ((size_t)kb * 512 + b * 64 + d) * 64 + kc;
            s1hi[o] = hh;
            s1lo[o] = (half_t)(v - (float)hh);
        }
}

// ---- K2/K3 unified: C[m][j] = sum_n (adj*mask)[m,n] * X[n][j]
// M=4096, N(j)=512, K=4096; BM=64, BN=128, BK=64, ks x2 partials.
// 512 threads = 8 waves (2m x 4n), wave tile 32x32 (fragment math = r13/r14).
// GRID 512 = 2 resident blocks/CU (LDS 48KB single-buffer -> capacity 3):
// co-resident blocks overlap barrier/staging stalls (m114). r14's mirror
// config (BN=64) doubled A-redundancy (FETCH 98->156MB); halving BM instead
// keeps nb=4 (A-FETCH flat) and only doubles X-reads (16MB, L2/L3-resident).
// Blocks sharing an A-panel are bid-stride-64 -> same XCD -> A L2-reuse.
// PASSES=3 (layer 1): A hi/lo + X hi/lo; PASSES=1 (layer 2): single fp16.
template<int PASSES>
__global__ __launch_bounds__(512) void gemm_bn(
    const float* __restrict__ adj, const float* __restrict__ mask,
    const half_t* __restrict__ xhi, const half_t* __restrict__ xlo,
    float* __restrict__ out0, float* __restrict__ out1)
{
    __shared__ half_t Ah[64 * 64];
    __shared__ half_t Al[PASSES == 3 ? 64 * 64 : 4];
    __shared__ half_t Xh[128 * 64];
    __shared__ half_t Xl[PASSES == 3 ? 128 * 64 : 4];
    const int t = threadIdx.x;
    const int l = t & 63, w = t >> 6, lr = l & 15, lg = l >> 4;
    const int wm = w >> 2, wn = w & 3;            // 2 m-tiles x 4 n-tiles
    const int bx = blockIdx.x;
    const int mt_ = bx & 63, ks = (bx >> 6) & 1, nb = bx >> 7;   // nb 0..3
    const int mBase = mt_ * 64, jBase = nb * 128;
    float* __restrict__ outp = ks ? out1 : out0;

    const f32x4 z = {0.f, 0.f, 0.f, 0.f};
    f32x4 acc[2][2] = {{z, z}, {z, z}};

    // staging slots: A = 64 rows x 8 chunks, 1 chunk/thread;
    //                X = 128 rows x 8 chunks, 2 chunks/thread (contig 64B).
    const int arow = t >> 3, akc = t & 7;
    const int ab = (arow * 128 + akc * 16) ^ ((arow & 7) << 4);
    const int xrow = t >> 2, xkc2 = (t & 3) * 2;
    const int xb0 = (xrow * 128 + xkc2 * 16) ^ ((xrow & 7) << 4);
    const int xb1 = (xrow * 128 + (xkc2 + 1) * 16) ^ ((xrow & 7) << 4);

    // prefetch registers (tile it+1)
    f32x4 pa0, pa1, pm0, pm1;
    half8 pxh0, pxh1, pxl0, pxl1;

#define ISSUE_LOADS(IT)                                                          \
    {                                                                            \
        const int kb = ks * 32 + (IT);                                           \
        size_t ga = (size_t)(mBase + arow) * NN + kb * 64 + akc * 8;             \
        pa0 = *(const f32x4*)(adj + ga);                                         \
        pa1 = *(const f32x4*)(adj + ga + 4);                                     \
        pm0 = *(const f32x4*)(mask + ga);                                        \
        pm1 = *(const f32x4*)(mask + ga + 4);                                    \
        size_t gx = ((size_t)kb * 512 + jBase + xrow) * 64 + xkc2 * 8;           \
        pxh0 = *(const half8*)(xhi + gx);                                        \
        pxh1 = *(const half8*)(xhi + gx + 8);                                    \
        if constexpr (PASSES == 3) {                                             \
            pxl0 = *(const half8*)(xlo + gx);                                    \
            pxl1 = *(const half8*)(xlo + gx + 8);                                \
        }                                                                        \
    }

#define CONVERT_WRITE()                                                          \
    {                                                                            \
        half8 hv, lv;                                                            \
        _Pragma("unroll")                                                        \
        for (int jj = 0; jj < 4; ++jj) {                                         \
            float q0 = pa0[jj] * pm0[jj];                                        \
            float q1 = pa1[jj] * pm1[jj];                                        \
            half_t h0 = (half_t)q0, h1 = (half_t)q1;                             \
            hv[jj] = h0; hv[jj + 4] = h1;                                        \
            if constexpr (PASSES == 3) {                                         \
                lv[jj] = (half_t)(q0 - (float)h0);                               \
                lv[jj + 4] = (half_t)(q1 - (float)h1);                           \
            }                                                                    \
        }                                                                        \
        *(half8*)((char*)Ah + ab) = hv;                                          \
        *(half8*)((char*)Xh + xb0) = pxh0;                                       \
        *(half8*)((char*)Xh + xb1) = pxh1;                                       \
        if constexpr (PASSES == 3) {                                             \
            *(half8*)((char*)Al + ab) = lv;                                      \
            *(half8*)((char*)Xl + xb0) = pxl0;                                   \
            *(half8*)((char*)Xl + xb1) = pxl1;                                   \
        }                                                                        \
    }

    ISSUE_LOADS(0);

    for (int it = 0; it < 32; ++it) {
        CONVERT_WRITE();                           // LDS <- regs (tile it)
        __syncthreads();                           // tile ready
        if (it + 1 < 32) ISSUE_LOADS(it + 1);      // next-tile loads in flight
        __builtin_amdgcn_sched_barrier(0);         // ...pinned before compute
#pragma unroll
        for (int kk = 0; kk < 2; ++kk) {
            half8 fa_h[2], fa_l[2], fx_h[2], fx_l[2];
#pragma unroll
            for (int mt = 0; mt < 2; ++mt) {
                int r = wm * 32 + mt * 16 + lr;
                int byte = (r * 128 + kk * 64 + lg * 16) ^ ((r & 7) << 4);
                fa_h[mt] = *(const half8*)((const char*)Ah + byte);
                if constexpr (PASSES == 3)
                    fa_l[mt] = *(const half8*)((const char*)Al + byte);
            }
#pragma unroll
            for (int nt = 0; nt < 2; ++nt) {
                int r = wn * 32 + nt * 16 + lr;
                int byte = (r * 128 + kk * 64 + lg * 16) ^ ((r & 7) << 4);
                fx_h[nt] = *(const half8*)((const char*)Xh + byte);
                if constexpr (PASSES == 3)
                    fx_l[nt] = *(const half8*)((const char*)Xl + byte);
            }
            __builtin_amdgcn_sched_barrier(0);      // batch reads, one drain
#pragma unroll
            for (int mt = 0; mt < 2; ++mt)
#pragma unroll
                for (int nt = 0; nt < 2; ++nt) {
                    acc[mt][nt] = __builtin_amdgcn_mfma_f32_16x16x32_f16(fa_h[mt], fx_h[nt], acc[mt][nt], 0, 0, 0);
                    if constexpr (PASSES == 3) {
                        acc[mt][nt] = __builtin_amdgcn_mfma_f32_16x16x32_f16(fa_l[mt], fx_h[nt], acc[mt][nt], 0, 0, 0);
                        acc[mt][nt] = __builtin_amdgcn_mfma_f32_16x16x32_f16(fa_h[mt], fx_l[nt], acc[mt][nt], 0, 0, 0);
                    }
                }
        }
        __syncthreads();                           // all reads done before rewrite
    }

    // C store: row m' = mBase+wm*32+mt*16+lg*4+j4, col j' = jBase+wn*32+nt*16+lr
#pragma unroll
    for (int mt = 0; mt < 2; ++mt)
#pragma unroll
        for (int nt = 0; nt < 2; ++nt) {
            int jcol = jBase + wn * 32 + nt * 16 + lr;
#pragma unroll
            for (int j4 = 0; j4 < 4; ++j4) {
                int mrow = mBase + wm * 32 + mt * 16 + lg * 4 + j4;
                outp[(size_t)mrow * 512 + jcol] = acc[mt][nt][j4];
            }
        }
#undef ISSUE_LOADS
#undef CONVERT_WRITE
}

// ---- K2e: x1[kb][j][kc] = relu(xp0+xp1+b1[j&63]) — SINGLE fp16 (one-hop error)
__global__ __launch_bounds__(256) void k2e(
    const float* __restrict__ p0, const float* __restrict__ p1,
    const float* __restrict__ b1,
    half_t* __restrict__ x1s)
{
    int base = blockIdx.x * 256 + threadIdx.x;
#pragma unroll
    for (int rpt = 0; rpt < 4; ++rpt) {
        int idx4 = base + rpt * 131072;
        int m = idx4 >> 7, jq = idx4 & 127;
        int j0 = jq * 4, d0 = j0 & 63;
        size_t e = (size_t)m * 512 + j0;
        f32x4 v = *(const f32x4*)(p0 + e);
        f32x4 u = *(const f32x4*)(p1 + e);
        f32x4 bb = *(const f32x4*)(b1 + d0);
        size_t obase = ((size_t)(m >> 6) * 512 + j0) * 64 + (m & 63);
#pragma unroll
        for (int jj = 0; jj < 4; ++jj) {
            float x = v[jj] + u[jj] + bb[jj];
            x = fmaxf(x, 0.f);
            x1s[obase + (size_t)jj * 64] = (half_t)x;
        }
    }
}

// ---- K4: cc = Y@W2 + b2 (fp32, full W2 in LDS, static acc indices) + LSTM pointwise.
__global__ __launch_bounds__(256) void k4_final(
    const float* __restrict__ y0, const float* __restrict__ y1,
    const float* __restrict__ w2, const float* __restrict__ b2,
    const float* __restrict__ ccur,
    float* __restrict__ outh, float* __restrict__ outc)
{
    __shared__ float Yt[64 * 64];
    __shared__ float W2s[64 * 256];
    const int t = threadIdx.x;
    const int cb = t & 15, rb = t >> 4;
    const int rowBase = blockIdx.x * 64;
    const int bIdx = rowBase >> 12, mBase = rowBase & 4095;

#pragma unroll
    for (int i = 0; i < 4; ++i) {
        int id4 = t + i * 256;
        int r = id4 >> 4, dc = id4 & 15;
        size_t g = (size_t)(mBase + r) * 512 + bIdx * 64 + dc * 4;
        f32x4 v = *(const f32x4*)(y0 + g);
        f32x4 u = *(const f32x4*)(y1 + g);
#pragma unroll
        for (int jj = 0; jj < 4; ++jj) Yt[(dc * 4 + jj) * 64 + r] = v[jj] + u[jj];
    }
#pragma unroll
    for (int i = 0; i < 16; ++i) {
        int id4 = t + i * 256;
        *(f32x4*)(W2s + id4 * 4) = *(const f32x4*)(w2 + id4 * 4);
    }
    __syncthreads();

    const f32x4 z = {0.f, 0.f, 0.f, 0.f};
    f32x4 accG[4][4];
#pragma unroll
    for (int g = 0; g < 4; ++g)
#pragma unroll
        for (int r8 = 0; r8 < 4; ++r8) accG[g][r8] = z;

    for (int d = 0; d < 64; ++d) {
        f32x4 y4 = *(const f32x4*)(Yt + d * 64 + rb * 4);
#pragma unroll
        for (int g = 0; g < 4; ++g) {
            f32x4 w4 = *(const f32x4*)(W2s + d * 256 + g * 64 + cb * 4);
#pragma unroll
            for (int r8 = 0; r8 < 4; ++r8) accG[g][r8] += w4 * y4[r8];
        }
    }

    float b2i[4], b2f[4], b2o[4], b2g[4];
#pragma unroll
    for (int jj = 0; jj < 4; ++jj) {
        b2i[jj] = b2[0 * 64 + cb * 4 + jj];
        b2f[jj] = b2[1 * 64 + cb * 4 + jj];
        b2o[jj] = b2[2 * 64 + cb * 4 + jj];
        b2g[jj] = b2[3 * 64 + cb * 4 + jj];
    }
#pragma unroll
    for (int r8 = 0; r8 < 4; ++r8) {
        int row = rowBase + rb * 4 + r8;
        f32x4 c4 = *(const f32x4*)(ccur + (size_t)row * 64 + cb * 4);
        f32x4 hv, cv;
#pragma unroll
        for (int jj = 0; jj < 4; ++jj) {
            float ii = sigmoidf_(accG[0][r8][jj] + b2i[jj]);
            float ff = sigmoidf_(accG[1][r8][jj] + b2f[jj]);
            float oo = sigmoidf_(accG[2][r8][jj] + b2o[jj]);
            float gg = tanhf_(accG[3][r8][jj] + b2g[jj]);
            float cn = ff * c4[jj] + ii * gg;
            float hn = oo * tanhf_(cn);
            hv[jj] = hn;
            cv[jj] = cn;
        }
        *(f32x4*)(outh + (size_t)row * 64 + cb * 4) = hv;
        *(f32x4*)(outc + (size_t)row * 64 + cb * 4) = cv;
    }
}

extern "C" void kernel_launch(void* const* d_in, const int* in_sizes, int n_in,
                              void* d_out, int out_size, void* d_ws, size_t ws_size,
                              hipStream_t stream) {
    const float* inp   = (const float*)d_in[0];
    const float* hcur  = (const float*)d_in[1];
    const float* ccur  = (const float*)d_in[2];
    const float* adj   = (const float*)d_in[3];
    const float* w1    = (const float*)d_in[4];
    const float* mask1 = (const float*)d_in[5];
    const float* b1    = (const float*)d_in[6];
    const float* w2    = (const float*)d_in[7];
    const float* mask2 = (const float*)d_in[8];
    const float* b2    = (const float*)d_in[9];

    char* ws = (char*)d_ws;
    half_t* w1thi = (half_t*)(ws + OFF_W1THI);
    half_t* w1tlo = (half_t*)(ws + OFF_W1TLO);
    half_t* s1hi  = (half_t*)(ws + OFF_S1HI);
    half_t* s1lo  = (half_t*)(ws + OFF_S1LO);
    half_t* x1s   = (half_t*)(ws + OFF_S1HI);   // alias: s1 dead after layer-1 gemm
    float*  xp0   = (float*)(ws + OFF_XP0);
    float*  xp1   = (float*)(ws + OFF_XP1);
    float*  y0    = (float*)(ws + OFF_XP0);     // alias: xp dead after k2e
    float*  y1    = (float*)(ws + OFF_XP1);

    float* hout = (float*)d_out;
    float* cout = hout + (size_t)8 * 4096 * 64;

    prep_w1t<<<24, 256, 0, stream>>>(w1, w1thi, w1tlo);
    k1_gemm<<<512, 256, 0, stream>>>(inp, hcur, w1thi, w1tlo, s1hi, s1lo);
    gemm_bn<3><<<512, 512, 0, stream>>>(adj, mask1, s1hi, s1lo, xp0, xp1);
    k2e<<<512, 256, 0, stream>>>(xp0, xp1, b1, x1s);
    gemm_bn<1><<<512, 512, 0, stream>>>(adj, mask2, x1s, x1s, y0, y1);
    k4_final<<<512, 256, 0, stream>>>(y0, y1, w2, b2, ccur, hout, cout);
}